// Round 12
// baseline (211.688 us; speedup 1.0000x reference)
//
#include <hip/hip_runtime.h>

// MPNN regression. R25: R24 base (190.8 us best) + full-row aggregate. The
// col-quarter split (blockIdx.y=4) visited each gathered 1KB row as 4
// temporally-scattered 256B reads from different blocks and re-read
// cursor/srcs 4x. Now one block-unit handles the FULL 512-col row: 16 nodes
// x 16 lanes, each lane walks 4x16B along the row (a[4][8] accum, 2-way src
// unroll). Aggregate units 2500 -> 625, index traffic /4, rows streamed.
// aggp grid = 1280 P-GEMM blocks + 625 gather blocks. Everything else
// byte-identical to R24 (m114 overlap: P rides the gather's idle MFMA).

typedef _Float16 half8 __attribute__((ext_vector_type(8)));
typedef float float4v __attribute__((ext_vector_type(4)));

#define ASYNC_COPY16(gptr, lptr)                                              \
    __builtin_amdgcn_global_load_lds(                                         \
        (const __attribute__((address_space(1))) void*)(gptr),                \
        (__attribute__((address_space(3))) void*)(lptr), 16, 0, 0)

// packed addr (halfs) for element (m,k) of a [*,K] matrix, KT = K/64:
//   ((m/64*KT + k/64)*8 + (k%64)/8)*512 + (m%64)*8 + k%8

// ------ fp16 MFMA GEMM body, packed inputs, compile-time specialized --------
// MODE: 0 = packC + bias + relu; 1 = row-major + bias + relu;
//       2 = frag-layout P out (no bias/relu); 3 = fused final dot -> atomicAdd
template<bool PIN, int MODE, int KTA, int KTW, int KTW0>
__device__ __forceinline__ void gemm_body(int id,
    const _Float16* __restrict__ A,
    const _Float16* __restrict__ Wt,
    const float* __restrict__ bias, _Float16* __restrict__ C,
    int M, int Mtiles,
    const _Float16* __restrict__ Pin,
    const float* __restrict__ Wout, const float* __restrict__ bout,
    float* __restrict__ outp)
{
    __shared__ _Float16 As[4096];   // [ch 0..7][row 0..63][8]  8 KB
    __shared__ _Float16 Bs[4096];

    const int tid  = threadIdx.x;
    const int wave = tid >> 6, lane = tid & 63;

    // swizzle: 8 pn-panels of one mt on consecutive ids == cxcd (mod 8)
    const int cxcd = id & 7, j = id >> 3;
    const int mt = cxcd + 8 * (j >> 3);
    if (mt >= Mtiles) return;
    const int pn = j & 7;
    const int bm = mt * 64, bn = pn * 64;

    const int wr = (wave >> 1) * 32, wc = (wave & 1) * 32;
    const int m16 = lane & 15, quad = lane >> 4;

    float4v acc[2][2] = {};
    if (PIN) {   // acc-init from fragment-layout partial (P = h @ updW_top)
        const _Float16* Pt = Pin + (size_t)(mt * 8 + pn) * 4096
                                 + wave * 64 + lane;
        #pragma unroll
        for (int i = 0; i < 2; ++i)
            #pragma unroll
            for (int j2 = 0; j2 < 2; ++j2)
                #pragma unroll
                for (int rg = 0; rg < 4; ++rg)
                    acc[i][j2][rg] = (float)Pt[((i * 2 + j2) * 4 + rg) * 256];
    }
    float bv[2] = {0.f, 0.f};
    if (MODE != 2) {
        #pragma unroll
        for (int jj = 0; jj < 2; ++jj) bv[jj] = bias[bn + wc + jj * 16 + m16];
    }

    for (int kt = 0; kt < KTA; ++kt) {
        const _Float16* Ab = A  + (size_t)(mt * KTA + kt) * 4096;
        const _Float16* Wb = Wt + (size_t)(pn * KTW + KTW0 + kt) * 4096;
        #pragma unroll
        for (int t = 0; t < 2; ++t) {
            const int q = t * 4 + wave;   // 1 KB chunk; dest = base + lane*16
            ASYNC_COPY16(Ab + q * 512 + lane * 8, (char*)As + q * 1024);
            ASYNC_COPY16(Wb + q * 512 + lane * 8, (char*)Bs + q * 1024);
        }
        __syncthreads();
        #pragma unroll
        for (int c = 0; c < 2; ++c) {
            half8 af[2], bf[2];
            #pragma unroll
            for (int i2 = 0; i2 < 2; ++i2)
                af[i2] = *(const half8*)
                    &As[((c * 4 + quad) * 64 + wr + i2 * 16 + m16) * 8];
            #pragma unroll
            for (int j2 = 0; j2 < 2; ++j2)
                bf[j2] = *(const half8*)
                    &Bs[((c * 4 + quad) * 64 + wc + j2 * 16 + m16) * 8];
            #pragma unroll
            for (int i2 = 0; i2 < 2; ++i2)
                #pragma unroll
                for (int j2 = 0; j2 < 2; ++j2)
                    acc[i2][j2] = __builtin_amdgcn_mfma_f32_16x16x32_f16(
                        af[i2], bf[j2], acc[i2][j2], 0, 0, 0);
        }
        __syncthreads();
    }

    if (MODE == 3) {
        // fused epilogue: out[row] += sum_cols relu(v) * Wout[col]  (+ b_out once)
        #pragma unroll
        for (int i = 0; i < 2; ++i)
            #pragma unroll
            for (int rg = 0; rg < 4; ++rg) {
                const int r2 = wr + i * 16 + quad * 4 + rg;
                const int row = bm + r2;
                float pr = 0.f;
                #pragma unroll
                for (int j2 = 0; j2 < 2; ++j2) {
                    float v = fmaxf(acc[i][j2][rg] + bv[j2], 0.f);
                    pr += v * Wout[bn + wc + j2 * 16 + m16];
                }
                pr += __shfl_xor(pr, 1);
                pr += __shfl_xor(pr, 2);
                pr += __shfl_xor(pr, 4);
                pr += __shfl_xor(pr, 8);
                if (m16 == 0 && row < M)
                    atomicAdd(&outp[row],
                              pr + ((pn == 0 && wc == 0) ? bout[0] : 0.f));
            }
        return;
    }

    if (MODE == 2) {
        // frag-layout P out: 128B/wave coalesced per frag
        _Float16* Pt = C + (size_t)(mt * 8 + pn) * 4096 + wave * 64 + lane;
        #pragma unroll
        for (int i = 0; i < 2; ++i)
            #pragma unroll
            for (int j2 = 0; j2 < 2; ++j2)
                #pragma unroll
                for (int rg = 0; rg < 4; ++rg)
                    Pt[((i * 2 + j2) * 4 + rg) * 256] = (_Float16)acc[i][j2][rg];
        return;
    }

    // MODE 0/1: D layout col=lane&15, row=quad*4+reg; relu + bias
    #pragma unroll
    for (int i = 0; i < 2; ++i)
        #pragma unroll
        for (int rg = 0; rg < 4; ++rg) {
            const int r2 = wr + i * 16 + quad * 4 + rg;
            const int row = bm + r2;
            if (row >= M) continue;
            #pragma unroll
            for (int j2 = 0; j2 < 2; ++j2) {
                float v = fmaxf(acc[i][j2][rg] + bv[j2], 0.f);
                const int coff = wc + j2 * 16 + m16;
                if (MODE == 0) {
                    C[(size_t)((mt * 8 + pn) * 8 + (coff >> 3)) * 512
                      + r2 * 8 + (coff & 7)] = (_Float16)v;
                } else {
                    C[(size_t)row * 512 + bn + coff] = (_Float16)v;
                }
            }
        }
}

// msg: relu(A@W1 + b1) -> row-major
__global__ __launch_bounds__(256) void gemm_msg(
    const _Float16* __restrict__ A, const _Float16* __restrict__ W1,
    const float* __restrict__ b1, _Float16* __restrict__ C1,
    int M, int Mtiles)
{
    gemm_body<false, 1, 8, 8, 0>(blockIdx.x, A, W1, b1, C1,
        M, Mtiles, nullptr, nullptr, nullptr, nullptr);
}

// upd0: Pin-init + aggr@W_bot (K=512, W ktiles 8..15) -> packed C
__global__ __launch_bounds__(256) void gemm_upd_pack(
    const _Float16* __restrict__ A, const _Float16* __restrict__ Wt,
    const float* __restrict__ bias, _Float16* __restrict__ C,
    int M, int Mtiles, const _Float16* __restrict__ Pin)
{
    gemm_body<true, 0, 8, 16, 8>(blockIdx.x, A, Wt, bias, C,
        M, Mtiles, Pin, nullptr, nullptr, nullptr);
}

// upd1: Pin-init + aggr@W_bot + fused final dot -> atomicAdd out
__global__ __launch_bounds__(256) void gemm_upd_out(
    const _Float16* __restrict__ A, const _Float16* __restrict__ Wt,
    const float* __restrict__ bias,
    int M, int Mtiles, const _Float16* __restrict__ Pin,
    const float* __restrict__ Wout, const float* __restrict__ bout,
    float* __restrict__ outp)
{
    gemm_body<true, 3, 8, 16, 8>(blockIdx.x, A, Wt, bias, nullptr,
        M, Mtiles, Pin, Wout, bout, outp);
}

// -- aggregation body: FULL-ROW bucket gather, row-major in, packed out ------
// 16 nodes x 16 lanes per block-unit; each lane walks 4x16B along the row.
__device__ __forceinline__ void aggregate_body(
    const _Float16* __restrict__ hmr, const int* __restrict__ cursor,
    const int* __restrict__ srcs, _Float16* __restrict__ ag, int n, int ab)
{
    const int tid  = threadIdx.x;
    const int l16  = tid & 15;
    const int node = ab * 16 + (tid >> 4);
    if (node >= n) return;
    const int beg = node * 64;
    const int end = beg + min(cursor[node], 64);
    float a[4][8] = {};
    int j = beg;
    for (; j + 1 < end; j += 2) {
        const _Float16* r0 = hmr + (size_t)srcs[j]     * 512 + l16 * 8;
        const _Float16* r1 = hmr + (size_t)srcs[j + 1] * 512 + l16 * 8;
        #pragma unroll
        for (int q = 0; q < 4; ++q) {
            const half8 v0 = *(const half8*)(r0 + q * 128);
            const half8 v1 = *(const half8*)(r1 + q * 128);
            #pragma unroll
            for (int i = 0; i < 8; ++i)
                a[q][i] += (float)v0[i] + (float)v1[i];
        }
    }
    for (; j < end; ++j) {
        const _Float16* r0 = hmr + (size_t)srcs[j] * 512 + l16 * 8;
        #pragma unroll
        for (int q = 0; q < 4; ++q) {
            const half8 v = *(const half8*)(r0 + q * 128);
            #pragma unroll
            for (int i = 0; i < 8; ++i) a[q][i] += (float)v[i];
        }
    }
    #pragma unroll
    for (int q = 0; q < 4; ++q) {
        const int c8 = q * 128 + l16 * 8;
        half8 o;
        #pragma unroll
        for (int i = 0; i < 8; ++i) o[i] = (_Float16)a[q][i];
        *(half8*)(ag + (size_t)(((node >> 6) * 8 + (c8 >> 6)) * 8 + ((c8 >> 3) & 7)) * 512
                  + (node & 63) * 8) = o;
    }
}

// ---- combo: P-GEMM (blocks [0,gemmBlocks)) || aggregate (rest) -------------
// P blocks dispatched FIRST so they're CU-resident while the latency-bound
// gather streams through — MFMA pipes run P under the gather's idle slots.
__global__ __launch_bounds__(256) void aggp(
    const _Float16* __restrict__ hmr, const int* __restrict__ cursor,
    const int* __restrict__ srcs, _Float16* __restrict__ ag, int n,
    const _Float16* __restrict__ A, const _Float16* __restrict__ W2,
    _Float16* __restrict__ P, int Mtiles, int gemmBlocks)
{
    const int b = blockIdx.x;
    if (b < gemmBlocks) {
        gemm_body<false, 2, 8, 16, 0>(b, A, W2, nullptr, P,
            n, Mtiles, nullptr, nullptr, nullptr, nullptr);
        return;
    }
    aggregate_body(hmr, cursor, srcs, ag, n, b - gemmBlocks);
}

// -------- transpose unit: src f32 [R,512] tile -> packed W^T [512,R] --------
__device__ __forceinline__ void transpose_unit(
    const float* __restrict__ src, _Float16* __restrict__ dst, int R, int tb)
{
    const int rtiles = R >> 5;
    const int r0 = (tb % rtiles) * 32, c0 = (tb / rtiles) * 32;
    const int KT = R >> 6;
    __shared__ float t[32][33];
    const int tid = threadIdx.x;
    const int tx = tid & 31, ty = tid >> 5;
    #pragma unroll
    for (int i = 0; i < 32; i += 8)
        t[ty + i][tx] = src[(size_t)(r0 + ty + i) * 512 + c0 + tx];
    __syncthreads();
    if (tid < 128) {
        const int n  = c0 + (tid >> 2);        // packed row (0..511)
        const int k0 = r0 + (tid & 3) * 8;     // packed col base (8-aligned)
        half8 o;
        #pragma unroll
        for (int j2 = 0; j2 < 8; ++j2)
            o[j2] = (_Float16)t[(tid & 3) * 8 + j2][tid >> 2];
        *(half8*)&dst[(size_t)(((n >> 6) * KT + (k0 >> 6)) * 8 + ((k0 >> 3) & 7)) * 512
                      + (n & 63) * 8] = o;
    }
}

// ---- fused: in-GEMM h0 || bucket fill || deferred msg/upd transposes -------
__global__ __launch_bounds__(256) void fill_ingemm(
    const int* __restrict__ eidx, int* __restrict__ cursor,
    int* __restrict__ srcs, int E,
    const _Float16* __restrict__ xb, const _Float16* __restrict__ WinT,
    const float* __restrict__ b_in, _Float16* __restrict__ B0,
    int M, int Mtiles,
    const float* __restrict__ msg_W, _Float16* __restrict__ msgT,
    const float* __restrict__ upd_W, _Float16* __restrict__ updT)
{
    const int gemmU = ((Mtiles + 7) >> 3) * 64;
    const int fillU = (E + 255) >> 8;
    const int b = blockIdx.x;
    if (b < gemmU) {
        gemm_body<false, 0, 4, 4, 0>(b, xb, WinT, b_in, B0,
            M, Mtiles, nullptr, nullptr, nullptr, nullptr);
        return;
    }
    if (b < gemmU + fillU) {
        const int e = (b - gemmU) * 256 + threadIdx.x;
        if (e < E) {
            const int d = eidx[E + e];
            const int pos = atomicAdd(&cursor[d], 1);
            if (pos < 64) srcs[d * 64 + pos] = eidx[e];   // never clamps: P~e^-30
        }
        return;
    }
    const int tB = b - gemmU - fillU;          // 0..1535
    if (tB < 256)       transpose_unit(msg_W,              msgT,              512,  tB);
    else if (tB < 512)  transpose_unit(msg_W + 512 * 512,  msgT + 512 * 512,  512,  tB - 256);
    else if (tB < 1024) transpose_unit(upd_W,              updT,              1024, tB - 512);
    else                transpose_unit(upd_W + 1024 * 512, updT + 512 * 1024, 1024, tB - 1024);
}

// --- prep: WinT transpose + x cast->packed + zero cursor & d_out -----------
__global__ __launch_bounds__(256) void prep(
    const float* __restrict__ W_in,  _Float16* __restrict__ WinT,
    const float* __restrict__ x,     _Float16* __restrict__ xb,
    int* __restrict__ cursor, float* __restrict__ outz,
    int n4, int M)
{
    const int b = blockIdx.x;
    const int tid = threadIdx.x;
    const int castU = (n4 + 255) >> 8;
    if (b < 128) {
        transpose_unit(W_in, WinT, 256, b);
    } else if (b < 128 + castU) {
        const int i = (b - 128) * 256 + tid;
        if (i < n4) {
            const float4 v = *(const float4*)(x + (size_t)i * 4);
            ushort4 s;
            union { _Float16 h; unsigned short u; } cv;
            cv.h = (_Float16)v.x; s.x = cv.u;
            cv.h = (_Float16)v.y; s.y = cv.u;
            cv.h = (_Float16)v.z; s.z = cv.u;
            cv.h = (_Float16)v.w; s.w = cv.u;
            const int f = i * 4;                 // flat half idx in [M,256]
            const int m = f >> 8, k = f & 255;
            *(ushort4*)((unsigned short*)xb
                + (size_t)(((m >> 6) * 4 + (k >> 6)) * 8 + ((k >> 3) & 7)) * 512
                + (m & 63) * 8 + (k & 7)) = s;
        }
    } else {
        const int zi = (b - 128 - castU) * 256 + tid;
        if (zi < M) { cursor[zi] = 0; outz[zi] = 0.f; }
    }
}

extern "C" void kernel_launch(void* const* d_in, const int* in_sizes, int n_in,
                              void* d_out, int out_size, void* d_ws, size_t ws_size,
                              hipStream_t stream)
{
    const float* x     = (const float*)d_in[0];
    const int*   eidx  = (const int*)  d_in[1];
    const float* W_in  = (const float*)d_in[2];
    const float* b_in  = (const float*)d_in[3];
    const float* msg_W = (const float*)d_in[4];
    const float* msg_b = (const float*)d_in[5];
    const float* upd_W = (const float*)d_in[6];
    const float* upd_b = (const float*)d_in[7];
    const float* W_out = (const float*)d_in[8];
    const float* b_out = (const float*)d_in[9];

    const int IN = 256, H = 512;
    const int M = in_sizes[0] / IN;   // 10000
    const int E = in_sizes[1] / 2;    // 160000
    const int Mtiles = (M + 63) / 64;
    const size_t Mt64 = (size_t)Mtiles * 64;

    _Float16* xb   = (_Float16*)d_ws;           // packed [Mt64, 256]
    _Float16* B0   = xb + Mt64 * IN;            // packed or row-major [Mt64,512]
    _Float16* B1   = B0 + Mt64 * H;
    _Float16* B2   = B1 + Mt64 * H;             // packed aggr
    _Float16* WinT = B2 + Mt64 * H;             // packed [512,256]
    _Float16* msgT = WinT + (size_t)H * IN;     // packed [2][512,512]
    _Float16* updT = msgT + (size_t)2 * H * H;  // packed [2][512,1024]
    int* cursor = (int*)(updT + (size_t)2 * H * 2 * H);   // [M]
    int* srcs   = cursor + M;                   // [M*64] dst-buckets
    _Float16* Pbuf = (_Float16*)(srcs + (size_t)M * 64);  // frag-layout [Mt64,512]

    const dim3 blk(256);
    const int gemmBlocks = ((Mtiles + 7) / 8) * 64;      // 1280
    const int aggrU = (M + 15) / 16;                     // 625 (full-row units)

    const int n4 = M * IN / 4;
    const int castU = (n4 + 255) / 256;
    const int fillU = (E + 255) / 256;
    const int zeroU = (M + 255) / 256;
    const int transU = 1536;                    // 256+256 msg + 512+512 upd tiles

    // prep: WinT + x cast + zero(cursor, d_out)
    prep<<<dim3(128 + castU + zeroU), blk, 0, stream>>>(
        W_in, WinT, x, xb, cursor, (float*)d_out, n4, M);
    // in-GEMM h0 || bucket fill || deferred msg/upd transposes
    fill_ingemm<<<dim3(gemmBlocks + fillU + transU), blk, 0, stream>>>(
        eidx, cursor, srcs, E, xb, WinT, b_in, B0, M, Mtiles,
        msg_W, msgT, upd_W, updT);

    // layer 0
    gemm_msg<<<dim3(gemmBlocks), blk, 0, stream>>>(
        B0, msgT, msg_b, B1, M, Mtiles);                 // msg0 -> B1 row-major
    aggp<<<dim3(gemmBlocks + aggrU), blk, 0, stream>>>(
        B1, cursor, srcs, B2, M,
        B0, updT, Pbuf, Mtiles, gemmBlocks);             // P0 || aggr0
    gemm_upd_pack<<<dim3(gemmBlocks), blk, 0, stream>>>(
        B2, updT, upd_b, B1, M, Mtiles, Pbuf);           // upd0 -> B1 packed
    // layer 1
    gemm_msg<<<dim3(gemmBlocks), blk, 0, stream>>>(
        B1, msgT + 512 * 512, msg_b + 512, B0, M, Mtiles); // msg1 -> B0 row-major
    aggp<<<dim3(gemmBlocks + aggrU), blk, 0, stream>>>(
        B0, cursor, srcs, B2, M,
        B1, updT + 512 * 1024, Pbuf, Mtiles, gemmBlocks);  // P1 || aggr1
    gemm_upd_out<<<dim3(gemmBlocks), blk, 0, stream>>>(
        B2, updT + 512 * 1024, upd_b + 512, M, Mtiles, Pbuf,
        W_out, b_out, (float*)d_out);
}

// Round 13
// 200.806 us; speedup vs baseline: 1.0542x; 1.0542x over previous
//
#include <hip/hip_runtime.h>

// MPNN regression. R26: R24 bodies byte-exact (190.8 us best; R25's full-row
// aggregate REVERTED: +21us — VGPR bloat throttled co-compiled P blocks AND
// 625 units killed gather TLP). One change: aggp role INTERLEAVING. R24
// dispatched 1280 P blocks first — at 4-5 blocks/CU they fill every CU slot,
// so the gather only overlaps at the drain boundary. Now b%3==0 -> P(b/3),
// else aggregate(b-(b+2)/3): both populations co-resident from dispatch
// start (m114 time~max regime across the whole kernel). Grid 3*1280=3840,
// 60 no-op tail blocks guarded. Aggregate = R24 quarter form verbatim.

typedef _Float16 half8 __attribute__((ext_vector_type(8)));
typedef float float4v __attribute__((ext_vector_type(4)));

#define ASYNC_COPY16(gptr, lptr)                                              \
    __builtin_amdgcn_global_load_lds(                                         \
        (const __attribute__((address_space(1))) void*)(gptr),                \
        (__attribute__((address_space(3))) void*)(lptr), 16, 0, 0)

// packed addr (halfs) for element (m,k) of a [*,K] matrix, KT = K/64:
//   ((m/64*KT + k/64)*8 + (k%64)/8)*512 + (m%64)*8 + k%8

// ------ fp16 MFMA GEMM body, packed inputs, compile-time specialized --------
// MODE: 0 = packC + bias + relu; 1 = row-major + bias + relu;
//       2 = frag-layout P out (no bias/relu); 3 = fused final dot -> atomicAdd
template<bool PIN, int MODE, int KTA, int KTW, int KTW0>
__device__ __forceinline__ void gemm_body(int id,
    const _Float16* __restrict__ A,
    const _Float16* __restrict__ Wt,
    const float* __restrict__ bias, _Float16* __restrict__ C,
    int M, int Mtiles,
    const _Float16* __restrict__ Pin,
    const float* __restrict__ Wout, const float* __restrict__ bout,
    float* __restrict__ outp)
{
    __shared__ _Float16 As[4096];   // [ch 0..7][row 0..63][8]  8 KB
    __shared__ _Float16 Bs[4096];

    const int tid  = threadIdx.x;
    const int wave = tid >> 6, lane = tid & 63;

    // swizzle: 8 pn-panels of one mt on consecutive ids == cxcd (mod 8)
    const int cxcd = id & 7, j = id >> 3;
    const int mt = cxcd + 8 * (j >> 3);
    if (mt >= Mtiles) return;
    const int pn = j & 7;
    const int bm = mt * 64, bn = pn * 64;

    const int wr = (wave >> 1) * 32, wc = (wave & 1) * 32;
    const int m16 = lane & 15, quad = lane >> 4;

    float4v acc[2][2] = {};
    if (PIN) {   // acc-init from fragment-layout partial (P = h @ updW_top)
        const _Float16* Pt = Pin + (size_t)(mt * 8 + pn) * 4096
                                 + wave * 64 + lane;
        #pragma unroll
        for (int i = 0; i < 2; ++i)
            #pragma unroll
            for (int j2 = 0; j2 < 2; ++j2)
                #pragma unroll
                for (int rg = 0; rg < 4; ++rg)
                    acc[i][j2][rg] = (float)Pt[((i * 2 + j2) * 4 + rg) * 256];
    }
    float bv[2] = {0.f, 0.f};
    if (MODE != 2) {
        #pragma unroll
        for (int jj = 0; jj < 2; ++jj) bv[jj] = bias[bn + wc + jj * 16 + m16];
    }

    for (int kt = 0; kt < KTA; ++kt) {
        const _Float16* Ab = A  + (size_t)(mt * KTA + kt) * 4096;
        const _Float16* Wb = Wt + (size_t)(pn * KTW + KTW0 + kt) * 4096;
        #pragma unroll
        for (int t = 0; t < 2; ++t) {
            const int q = t * 4 + wave;   // 1 KB chunk; dest = base + lane*16
            ASYNC_COPY16(Ab + q * 512 + lane * 8, (char*)As + q * 1024);
            ASYNC_COPY16(Wb + q * 512 + lane * 8, (char*)Bs + q * 1024);
        }
        __syncthreads();
        #pragma unroll
        for (int c = 0; c < 2; ++c) {
            half8 af[2], bf[2];
            #pragma unroll
            for (int i2 = 0; i2 < 2; ++i2)
                af[i2] = *(const half8*)
                    &As[((c * 4 + quad) * 64 + wr + i2 * 16 + m16) * 8];
            #pragma unroll
            for (int j2 = 0; j2 < 2; ++j2)
                bf[j2] = *(const half8*)
                    &Bs[((c * 4 + quad) * 64 + wc + j2 * 16 + m16) * 8];
            #pragma unroll
            for (int i2 = 0; i2 < 2; ++i2)
                #pragma unroll
                for (int j2 = 0; j2 < 2; ++j2)
                    acc[i2][j2] = __builtin_amdgcn_mfma_f32_16x16x32_f16(
                        af[i2], bf[j2], acc[i2][j2], 0, 0, 0);
        }
        __syncthreads();
    }

    if (MODE == 3) {
        // fused epilogue: out[row] += sum_cols relu(v) * Wout[col]  (+ b_out once)
        #pragma unroll
        for (int i = 0; i < 2; ++i)
            #pragma unroll
            for (int rg = 0; rg < 4; ++rg) {
                const int r2 = wr + i * 16 + quad * 4 + rg;
                const int row = bm + r2;
                float pr = 0.f;
                #pragma unroll
                for (int j2 = 0; j2 < 2; ++j2) {
                    float v = fmaxf(acc[i][j2][rg] + bv[j2], 0.f);
                    pr += v * Wout[bn + wc + j2 * 16 + m16];
                }
                pr += __shfl_xor(pr, 1);
                pr += __shfl_xor(pr, 2);
                pr += __shfl_xor(pr, 4);
                pr += __shfl_xor(pr, 8);
                if (m16 == 0 && row < M)
                    atomicAdd(&outp[row],
                              pr + ((pn == 0 && wc == 0) ? bout[0] : 0.f));
            }
        return;
    }

    if (MODE == 2) {
        // frag-layout P out: 128B/wave coalesced per frag
        _Float16* Pt = C + (size_t)(mt * 8 + pn) * 4096 + wave * 64 + lane;
        #pragma unroll
        for (int i = 0; i < 2; ++i)
            #pragma unroll
            for (int j2 = 0; j2 < 2; ++j2)
                #pragma unroll
                for (int rg = 0; rg < 4; ++rg)
                    Pt[((i * 2 + j2) * 4 + rg) * 256] = (_Float16)acc[i][j2][rg];
        return;
    }

    // MODE 0/1: D layout col=lane&15, row=quad*4+reg; relu + bias
    #pragma unroll
    for (int i = 0; i < 2; ++i)
        #pragma unroll
        for (int rg = 0; rg < 4; ++rg) {
            const int r2 = wr + i * 16 + quad * 4 + rg;
            const int row = bm + r2;
            if (row >= M) continue;
            #pragma unroll
            for (int j2 = 0; j2 < 2; ++j2) {
                float v = fmaxf(acc[i][j2][rg] + bv[j2], 0.f);
                const int coff = wc + j2 * 16 + m16;
                if (MODE == 0) {
                    C[(size_t)((mt * 8 + pn) * 8 + (coff >> 3)) * 512
                      + r2 * 8 + (coff & 7)] = (_Float16)v;
                } else {
                    C[(size_t)row * 512 + bn + coff] = (_Float16)v;
                }
            }
        }
}

// msg: relu(A@W1 + b1) -> row-major
__global__ __launch_bounds__(256) void gemm_msg(
    const _Float16* __restrict__ A, const _Float16* __restrict__ W1,
    const float* __restrict__ b1, _Float16* __restrict__ C1,
    int M, int Mtiles)
{
    gemm_body<false, 1, 8, 8, 0>(blockIdx.x, A, W1, b1, C1,
        M, Mtiles, nullptr, nullptr, nullptr, nullptr);
}

// upd0: Pin-init + aggr@W_bot (K=512, W ktiles 8..15) -> packed C
__global__ __launch_bounds__(256) void gemm_upd_pack(
    const _Float16* __restrict__ A, const _Float16* __restrict__ Wt,
    const float* __restrict__ bias, _Float16* __restrict__ C,
    int M, int Mtiles, const _Float16* __restrict__ Pin)
{
    gemm_body<true, 0, 8, 16, 8>(blockIdx.x, A, Wt, bias, C,
        M, Mtiles, Pin, nullptr, nullptr, nullptr);
}

// upd1: Pin-init + aggr@W_bot + fused final dot -> atomicAdd out
__global__ __launch_bounds__(256) void gemm_upd_out(
    const _Float16* __restrict__ A, const _Float16* __restrict__ Wt,
    const float* __restrict__ bias,
    int M, int Mtiles, const _Float16* __restrict__ Pin,
    const float* __restrict__ Wout, const float* __restrict__ bout,
    float* __restrict__ outp)
{
    gemm_body<true, 3, 8, 16, 8>(blockIdx.x, A, Wt, bias, nullptr,
        M, Mtiles, Pin, Wout, bout, outp);
}

// -- aggregation body: bucket gather, hmr row-major in, ag PACKED out --------
// R24 quarter form: block-unit ab -> 16 nodes x quarter (ab&3).
__device__ __forceinline__ void aggregate_body(
    const _Float16* __restrict__ hmr, const int* __restrict__ cursor,
    const int* __restrict__ srcs, _Float16* __restrict__ ag, int n, int ab)
{
    const int tid  = threadIdx.x;
    const int l16  = tid & 15;
    const int node = (ab >> 2) * 16 + (tid >> 4);
    if (node >= n) return;
    const int c8 = (ab & 3) * 128 + l16 * 8;
    const int beg = node * 64;
    const int end = beg + min(cursor[node], 64);
    float a[8] = {};
    int j = beg;
    for (; j + 3 < end; j += 4) {
        const half8 v0 = *(const half8*)(hmr + (size_t)srcs[j]     * 512 + c8);
        const half8 v1 = *(const half8*)(hmr + (size_t)srcs[j + 1] * 512 + c8);
        const half8 v2 = *(const half8*)(hmr + (size_t)srcs[j + 2] * 512 + c8);
        const half8 v3 = *(const half8*)(hmr + (size_t)srcs[j + 3] * 512 + c8);
        #pragma unroll
        for (int i = 0; i < 8; ++i)
            a[i] += ((float)v0[i] + (float)v1[i]) + ((float)v2[i] + (float)v3[i]);
    }
    for (; j < end; ++j) {
        const half8 v = *(const half8*)(hmr + (size_t)srcs[j] * 512 + c8);
        #pragma unroll
        for (int i = 0; i < 8; ++i) a[i] += (float)v[i];
    }
    half8 o;
    #pragma unroll
    for (int i = 0; i < 8; ++i) o[i] = (_Float16)a[i];
    *(half8*)(ag + (size_t)(((node >> 6) * 8 + (c8 >> 6)) * 8 + ((c8 >> 3) & 7)) * 512
              + (node & 63) * 8) = o;
}

// ---- combo: P-GEMM || aggregate, INTERLEAVED roles ------------------------
// b%3==0 -> P block b/3 (exactly gemmBlocks of them, grid = 3*gemmBlocks);
// else aggregate unit b-(b+2)/3 (guarded). Both populations co-resident
// from dispatch start -> gather latency hides under P's MFMA all kernel.
__global__ __launch_bounds__(256) void aggp(
    const _Float16* __restrict__ hmr, const int* __restrict__ cursor,
    const int* __restrict__ srcs, _Float16* __restrict__ ag, int n,
    const _Float16* __restrict__ A, const _Float16* __restrict__ W2,
    _Float16* __restrict__ P, int Mtiles, int aggrU)
{
    const int b = blockIdx.x;
    if (b % 3 == 0) {
        gemm_body<false, 2, 8, 16, 0>(b / 3, A, W2, nullptr, P,
            n, Mtiles, nullptr, nullptr, nullptr, nullptr);
        return;
    }
    const int ab = b - (b + 2) / 3;
    if (ab >= aggrU) return;
    aggregate_body(hmr, cursor, srcs, ag, n, ab);
}

// -------- transpose unit: src f32 [R,512] tile -> packed W^T [512,R] --------
__device__ __forceinline__ void transpose_unit(
    const float* __restrict__ src, _Float16* __restrict__ dst, int R, int tb)
{
    const int rtiles = R >> 5;
    const int r0 = (tb % rtiles) * 32, c0 = (tb / rtiles) * 32;
    const int KT = R >> 6;
    __shared__ float t[32][33];
    const int tid = threadIdx.x;
    const int tx = tid & 31, ty = tid >> 5;
    #pragma unroll
    for (int i = 0; i < 32; i += 8)
        t[ty + i][tx] = src[(size_t)(r0 + ty + i) * 512 + c0 + tx];
    __syncthreads();
    if (tid < 128) {
        const int n  = c0 + (tid >> 2);        // packed row (0..511)
        const int k0 = r0 + (tid & 3) * 8;     // packed col base (8-aligned)
        half8 o;
        #pragma unroll
        for (int j2 = 0; j2 < 8; ++j2)
            o[j2] = (_Float16)t[(tid & 3) * 8 + j2][tid >> 2];
        *(half8*)&dst[(size_t)(((n >> 6) * KT + (k0 >> 6)) * 8 + ((k0 >> 3) & 7)) * 512
                      + (n & 63) * 8] = o;
    }
}

// ---- fused: in-GEMM h0 || bucket fill || deferred msg/upd transposes -------
__global__ __launch_bounds__(256) void fill_ingemm(
    const int* __restrict__ eidx, int* __restrict__ cursor,
    int* __restrict__ srcs, int E,
    const _Float16* __restrict__ xb, const _Float16* __restrict__ WinT,
    const float* __restrict__ b_in, _Float16* __restrict__ B0,
    int M, int Mtiles,
    const float* __restrict__ msg_W, _Float16* __restrict__ msgT,
    const float* __restrict__ upd_W, _Float16* __restrict__ updT)
{
    const int gemmU = ((Mtiles + 7) >> 3) * 64;
    const int fillU = (E + 255) >> 8;
    const int b = blockIdx.x;
    if (b < gemmU) {
        gemm_body<false, 0, 4, 4, 0>(b, xb, WinT, b_in, B0,
            M, Mtiles, nullptr, nullptr, nullptr, nullptr);
        return;
    }
    if (b < gemmU + fillU) {
        const int e = (b - gemmU) * 256 + threadIdx.x;
        if (e < E) {
            const int d = eidx[E + e];
            const int pos = atomicAdd(&cursor[d], 1);
            if (pos < 64) srcs[d * 64 + pos] = eidx[e];   // never clamps: P~e^-30
        }
        return;
    }
    const int tB = b - gemmU - fillU;          // 0..1535
    if (tB < 256)       transpose_unit(msg_W,              msgT,              512,  tB);
    else if (tB < 512)  transpose_unit(msg_W + 512 * 512,  msgT + 512 * 512,  512,  tB - 256);
    else if (tB < 1024) transpose_unit(upd_W,              updT,              1024, tB - 512);
    else                transpose_unit(upd_W + 1024 * 512, updT + 512 * 1024, 1024, tB - 1024);
}

// --- prep: WinT transpose + x cast->packed + zero cursor & d_out -----------
__global__ __launch_bounds__(256) void prep(
    const float* __restrict__ W_in,  _Float16* __restrict__ WinT,
    const float* __restrict__ x,     _Float16* __restrict__ xb,
    int* __restrict__ cursor, float* __restrict__ outz,
    int n4, int M)
{
    const int b = blockIdx.x;
    const int tid = threadIdx.x;
    const int castU = (n4 + 255) >> 8;
    if (b < 128) {
        transpose_unit(W_in, WinT, 256, b);
    } else if (b < 128 + castU) {
        const int i = (b - 128) * 256 + tid;
        if (i < n4) {
            const float4 v = *(const float4*)(x + (size_t)i * 4);
            ushort4 s;
            union { _Float16 h; unsigned short u; } cv;
            cv.h = (_Float16)v.x; s.x = cv.u;
            cv.h = (_Float16)v.y; s.y = cv.u;
            cv.h = (_Float16)v.z; s.z = cv.u;
            cv.h = (_Float16)v.w; s.w = cv.u;
            const int f = i * 4;                 // flat half idx in [M,256]
            const int m = f >> 8, k = f & 255;
            *(ushort4*)((unsigned short*)xb
                + (size_t)(((m >> 6) * 4 + (k >> 6)) * 8 + ((k >> 3) & 7)) * 512
                + (m & 63) * 8 + (k & 7)) = s;
        }
    } else {
        const int zi = (b - 128 - castU) * 256 + tid;
        if (zi < M) { cursor[zi] = 0; outz[zi] = 0.f; }
    }
}

extern "C" void kernel_launch(void* const* d_in, const int* in_sizes, int n_in,
                              void* d_out, int out_size, void* d_ws, size_t ws_size,
                              hipStream_t stream)
{
    const float* x     = (const float*)d_in[0];
    const int*   eidx  = (const int*)  d_in[1];
    const float* W_in  = (const float*)d_in[2];
    const float* b_in  = (const float*)d_in[3];
    const float* msg_W = (const float*)d_in[4];
    const float* msg_b = (const float*)d_in[5];
    const float* upd_W = (const float*)d_in[6];
    const float* upd_b = (const float*)d_in[7];
    const float* W_out = (const float*)d_in[8];
    const float* b_out = (const float*)d_in[9];

    const int IN = 256, H = 512;
    const int M = in_sizes[0] / IN;   // 10000
    const int E = in_sizes[1] / 2;    // 160000
    const int Mtiles = (M + 63) / 64;
    const size_t Mt64 = (size_t)Mtiles * 64;

    _Float16* xb   = (_Float16*)d_ws;           // packed [Mt64, 256]
    _Float16* B0   = xb + Mt64 * IN;            // packed or row-major [Mt64,512]
    _Float16* B1   = B0 + Mt64 * H;
    _Float16* B2   = B1 + Mt64 * H;             // packed aggr
    _Float16* WinT = B2 + Mt64 * H;             // packed [512,256]
    _Float16* msgT = WinT + (size_t)H * IN;     // packed [2][512,512]
    _Float16* updT = msgT + (size_t)2 * H * H;  // packed [2][512,1024]
    int* cursor = (int*)(updT + (size_t)2 * H * 2 * H);   // [M]
    int* srcs   = cursor + M;                   // [M*64] dst-buckets
    _Float16* Pbuf = (_Float16*)(srcs + (size_t)M * 64);  // frag-layout [Mt64,512]

    const dim3 blk(256);
    const int gemmBlocks = ((Mtiles + 7) / 8) * 64;      // 1280
    const int aggrU = ((M + 15) / 16) * 4;               // 2500 (quarter units)
    const int aggpGrid = gemmBlocks * 3;                 // 3840 interleaved

    const int n4 = M * IN / 4;
    const int castU = (n4 + 255) / 256;
    const int fillU = (E + 255) / 256;
    const int zeroU = (M + 255) / 256;
    const int transU = 1536;                    // 256+256 msg + 512+512 upd tiles

    // prep: WinT + x cast + zero(cursor, d_out)
    prep<<<dim3(128 + castU + zeroU), blk, 0, stream>>>(
        W_in, WinT, x, xb, cursor, (float*)d_out, n4, M);
    // in-GEMM h0 || bucket fill || deferred msg/upd transposes
    fill_ingemm<<<dim3(gemmBlocks + fillU + transU), blk, 0, stream>>>(
        eidx, cursor, srcs, E, xb, WinT, b_in, B0, M, Mtiles,
        msg_W, msgT, upd_W, updT);

    // layer 0
    gemm_msg<<<dim3(gemmBlocks), blk, 0, stream>>>(
        B0, msgT, msg_b, B1, M, Mtiles);                 // msg0 -> B1 row-major
    aggp<<<dim3(aggpGrid), blk, 0, stream>>>(
        B1, cursor, srcs, B2, M,
        B0, updT, Pbuf, Mtiles, aggrU);                  // P0 || aggr0
    gemm_upd_pack<<<dim3(gemmBlocks), blk, 0, stream>>>(
        B2, updT, upd_b, B1, M, Mtiles, Pbuf);           // upd0 -> B1 packed
    // layer 1
    gemm_msg<<<dim3(gemmBlocks), blk, 0, stream>>>(
        B1, msgT + 512 * 512, msg_b + 512, B0, M, Mtiles); // msg1 -> B0 row-major
    aggp<<<dim3(aggpGrid), blk, 0, stream>>>(
        B0, cursor, srcs, B2, M,
        B1, updT + 512 * 1024, Pbuf, Mtiles, aggrU);       // P1 || aggr1
    gemm_upd_out<<<dim3(gemmBlocks), blk, 0, stream>>>(
        B2, updT + 512 * 1024, upd_b + 512, M, Mtiles, Pbuf,
        W_out, b_out, (float*)d_out);
}

// Round 14
// 187.842 us; speedup vs baseline: 1.1269x; 1.0690x over previous
//
#include <hip/hip_runtime.h>

// MPNN regression. R27: R24 byte-exact (190.8 us best; R26 interleave
// REVERTED +10 — it proved P is aggp's LONG leg, gather hides inside it)
// + T5 s_setprio on aggp's P population. Catalog m190/m191: setprio is null
// on lockstep GEMM but +4-7% when a CU hosts waves of DIFFERENT roles —
// aggp is exactly that (MFMA-bound P waves + latency-stalled gather waves).
// P waves run at prio 1 for their lifetime: MFMA leg wins issue arbitration
// against gather waves, which are memory-stalled anyway. Zero-risk hint;
// everything else identical to R24.

typedef _Float16 half8 __attribute__((ext_vector_type(8)));
typedef float float4v __attribute__((ext_vector_type(4)));

#define ASYNC_COPY16(gptr, lptr)                                              \
    __builtin_amdgcn_global_load_lds(                                         \
        (const __attribute__((address_space(1))) void*)(gptr),                \
        (__attribute__((address_space(3))) void*)(lptr), 16, 0, 0)

// packed addr (halfs) for element (m,k) of a [*,K] matrix, KT = K/64:
//   ((m/64*KT + k/64)*8 + (k%64)/8)*512 + (m%64)*8 + k%8

// ------ fp16 MFMA GEMM body, packed inputs, compile-time specialized --------
// MODE: 0 = packC + bias + relu; 1 = row-major + bias + relu;
//       2 = frag-layout P out (no bias/relu); 3 = fused final dot -> atomicAdd
template<bool PIN, int MODE, int KTA, int KTW, int KTW0>
__device__ __forceinline__ void gemm_body(int id,
    const _Float16* __restrict__ A,
    const _Float16* __restrict__ Wt,
    const float* __restrict__ bias, _Float16* __restrict__ C,
    int M, int Mtiles,
    const _Float16* __restrict__ Pin,
    const float* __restrict__ Wout, const float* __restrict__ bout,
    float* __restrict__ outp)
{
    __shared__ _Float16 As[4096];   // [ch 0..7][row 0..63][8]  8 KB
    __shared__ _Float16 Bs[4096];

    const int tid  = threadIdx.x;
    const int wave = tid >> 6, lane = tid & 63;

    // swizzle: 8 pn-panels of one mt on consecutive ids == cxcd (mod 8)
    const int cxcd = id & 7, j = id >> 3;
    const int mt = cxcd + 8 * (j >> 3);
    if (mt >= Mtiles) return;
    const int pn = j & 7;
    const int bm = mt * 64, bn = pn * 64;

    const int wr = (wave >> 1) * 32, wc = (wave & 1) * 32;
    const int m16 = lane & 15, quad = lane >> 4;

    float4v acc[2][2] = {};
    if (PIN) {   // acc-init from fragment-layout partial (P = h @ updW_top)
        const _Float16* Pt = Pin + (size_t)(mt * 8 + pn) * 4096
                                 + wave * 64 + lane;
        #pragma unroll
        for (int i = 0; i < 2; ++i)
            #pragma unroll
            for (int j2 = 0; j2 < 2; ++j2)
                #pragma unroll
                for (int rg = 0; rg < 4; ++rg)
                    acc[i][j2][rg] = (float)Pt[((i * 2 + j2) * 4 + rg) * 256];
    }
    float bv[2] = {0.f, 0.f};
    if (MODE != 2) {
        #pragma unroll
        for (int jj = 0; jj < 2; ++jj) bv[jj] = bias[bn + wc + jj * 16 + m16];
    }

    for (int kt = 0; kt < KTA; ++kt) {
        const _Float16* Ab = A  + (size_t)(mt * KTA + kt) * 4096;
        const _Float16* Wb = Wt + (size_t)(pn * KTW + KTW0 + kt) * 4096;
        #pragma unroll
        for (int t = 0; t < 2; ++t) {
            const int q = t * 4 + wave;   // 1 KB chunk; dest = base + lane*16
            ASYNC_COPY16(Ab + q * 512 + lane * 8, (char*)As + q * 1024);
            ASYNC_COPY16(Wb + q * 512 + lane * 8, (char*)Bs + q * 1024);
        }
        __syncthreads();
        #pragma unroll
        for (int c = 0; c < 2; ++c) {
            half8 af[2], bf[2];
            #pragma unroll
            for (int i2 = 0; i2 < 2; ++i2)
                af[i2] = *(const half8*)
                    &As[((c * 4 + quad) * 64 + wr + i2 * 16 + m16) * 8];
            #pragma unroll
            for (int j2 = 0; j2 < 2; ++j2)
                bf[j2] = *(const half8*)
                    &Bs[((c * 4 + quad) * 64 + wc + j2 * 16 + m16) * 8];
            #pragma unroll
            for (int i2 = 0; i2 < 2; ++i2)
                #pragma unroll
                for (int j2 = 0; j2 < 2; ++j2)
                    acc[i2][j2] = __builtin_amdgcn_mfma_f32_16x16x32_f16(
                        af[i2], bf[j2], acc[i2][j2], 0, 0, 0);
        }
        __syncthreads();
    }

    if (MODE == 3) {
        // fused epilogue: out[row] += sum_cols relu(v) * Wout[col]  (+ b_out once)
        #pragma unroll
        for (int i = 0; i < 2; ++i)
            #pragma unroll
            for (int rg = 0; rg < 4; ++rg) {
                const int r2 = wr + i * 16 + quad * 4 + rg;
                const int row = bm + r2;
                float pr = 0.f;
                #pragma unroll
                for (int j2 = 0; j2 < 2; ++j2) {
                    float v = fmaxf(acc[i][j2][rg] + bv[j2], 0.f);
                    pr += v * Wout[bn + wc + j2 * 16 + m16];
                }
                pr += __shfl_xor(pr, 1);
                pr += __shfl_xor(pr, 2);
                pr += __shfl_xor(pr, 4);
                pr += __shfl_xor(pr, 8);
                if (m16 == 0 && row < M)
                    atomicAdd(&outp[row],
                              pr + ((pn == 0 && wc == 0) ? bout[0] : 0.f));
            }
        return;
    }

    if (MODE == 2) {
        // frag-layout P out: 128B/wave coalesced per frag
        _Float16* Pt = C + (size_t)(mt * 8 + pn) * 4096 + wave * 64 + lane;
        #pragma unroll
        for (int i = 0; i < 2; ++i)
            #pragma unroll
            for (int j2 = 0; j2 < 2; ++j2)
                #pragma unroll
                for (int rg = 0; rg < 4; ++rg)
                    Pt[((i * 2 + j2) * 4 + rg) * 256] = (_Float16)acc[i][j2][rg];
        return;
    }

    // MODE 0/1: D layout col=lane&15, row=quad*4+reg; relu + bias
    #pragma unroll
    for (int i = 0; i < 2; ++i)
        #pragma unroll
        for (int rg = 0; rg < 4; ++rg) {
            const int r2 = wr + i * 16 + quad * 4 + rg;
            const int row = bm + r2;
            if (row >= M) continue;
            #pragma unroll
            for (int j2 = 0; j2 < 2; ++j2) {
                float v = fmaxf(acc[i][j2][rg] + bv[j2], 0.f);
                const int coff = wc + j2 * 16 + m16;
                if (MODE == 0) {
                    C[(size_t)((mt * 8 + pn) * 8 + (coff >> 3)) * 512
                      + r2 * 8 + (coff & 7)] = (_Float16)v;
                } else {
                    C[(size_t)row * 512 + bn + coff] = (_Float16)v;
                }
            }
        }
}

// msg: relu(A@W1 + b1) -> row-major
__global__ __launch_bounds__(256) void gemm_msg(
    const _Float16* __restrict__ A, const _Float16* __restrict__ W1,
    const float* __restrict__ b1, _Float16* __restrict__ C1,
    int M, int Mtiles)
{
    gemm_body<false, 1, 8, 8, 0>(blockIdx.x, A, W1, b1, C1,
        M, Mtiles, nullptr, nullptr, nullptr, nullptr);
}

// upd0: Pin-init + aggr@W_bot (K=512, W ktiles 8..15) -> packed C
__global__ __launch_bounds__(256) void gemm_upd_pack(
    const _Float16* __restrict__ A, const _Float16* __restrict__ Wt,
    const float* __restrict__ bias, _Float16* __restrict__ C,
    int M, int Mtiles, const _Float16* __restrict__ Pin)
{
    gemm_body<true, 0, 8, 16, 8>(blockIdx.x, A, Wt, bias, C,
        M, Mtiles, Pin, nullptr, nullptr, nullptr);
}

// upd1: Pin-init + aggr@W_bot + fused final dot -> atomicAdd out
__global__ __launch_bounds__(256) void gemm_upd_out(
    const _Float16* __restrict__ A, const _Float16* __restrict__ Wt,
    const float* __restrict__ bias,
    int M, int Mtiles, const _Float16* __restrict__ Pin,
    const float* __restrict__ Wout, const float* __restrict__ bout,
    float* __restrict__ outp)
{
    gemm_body<true, 3, 8, 16, 8>(blockIdx.x, A, Wt, bias, nullptr,
        M, Mtiles, Pin, Wout, bout, outp);
}

// -- aggregation body: bucket gather, hmr row-major in, ag PACKED out --------
__device__ __forceinline__ void aggregate_body(
    const _Float16* __restrict__ hmr, const int* __restrict__ cursor,
    const int* __restrict__ srcs, _Float16* __restrict__ ag, int n, int ab)
{
    const int tid  = threadIdx.x;
    const int l16  = tid & 15;
    const int node = (ab >> 2) * 16 + (tid >> 4);
    if (node >= n) return;
    const int c8 = (ab & 3) * 128 + l16 * 8;
    const int beg = node * 64;
    const int end = beg + min(cursor[node], 64);
    float a[8] = {};
    int j = beg;
    for (; j + 3 < end; j += 4) {
        const half8 v0 = *(const half8*)(hmr + (size_t)srcs[j]     * 512 + c8);
        const half8 v1 = *(const half8*)(hmr + (size_t)srcs[j + 1] * 512 + c8);
        const half8 v2 = *(const half8*)(hmr + (size_t)srcs[j + 2] * 512 + c8);
        const half8 v3 = *(const half8*)(hmr + (size_t)srcs[j + 3] * 512 + c8);
        #pragma unroll
        for (int i = 0; i < 8; ++i)
            a[i] += ((float)v0[i] + (float)v1[i]) + ((float)v2[i] + (float)v3[i]);
    }
    for (; j < end; ++j) {
        const half8 v = *(const half8*)(hmr + (size_t)srcs[j] * 512 + c8);
        #pragma unroll
        for (int i = 0; i < 8; ++i) a[i] += (float)v[i];
    }
    half8 o;
    #pragma unroll
    for (int i = 0; i < 8; ++i) o[i] = (_Float16)a[i];
    *(half8*)(ag + (size_t)(((node >> 6) * 8 + (c8 >> 6)) * 8 + ((c8 >> 3) & 7)) * 512
              + (node & 63) * 8) = o;
}

// ---- combo: P-GEMM (blocks [0,gemmBlocks)) || aggregate (rest) -------------
// P blocks dispatched FIRST (R26 proved P is the long leg; gather backfills).
// T5: P waves run at priority 1 — they win issue arbitration on CUs shared
// with latency-stalled gather waves.
__global__ __launch_bounds__(256) void aggp(
    const _Float16* __restrict__ hmr, const int* __restrict__ cursor,
    const int* __restrict__ srcs, _Float16* __restrict__ ag, int n,
    const _Float16* __restrict__ A, const _Float16* __restrict__ W2,
    _Float16* __restrict__ P, int Mtiles, int gemmBlocks)
{
    const int b = blockIdx.x;
    if (b < gemmBlocks) {
        __builtin_amdgcn_s_setprio(1);
        gemm_body<false, 2, 8, 16, 0>(b, A, W2, nullptr, P,
            n, Mtiles, nullptr, nullptr, nullptr, nullptr);
        __builtin_amdgcn_s_setprio(0);
        return;
    }
    aggregate_body(hmr, cursor, srcs, ag, n, b - gemmBlocks);
}

// -------- transpose unit: src f32 [R,512] tile -> packed W^T [512,R] --------
__device__ __forceinline__ void transpose_unit(
    const float* __restrict__ src, _Float16* __restrict__ dst, int R, int tb)
{
    const int rtiles = R >> 5;
    const int r0 = (tb % rtiles) * 32, c0 = (tb / rtiles) * 32;
    const int KT = R >> 6;
    __shared__ float t[32][33];
    const int tid = threadIdx.x;
    const int tx = tid & 31, ty = tid >> 5;
    #pragma unroll
    for (int i = 0; i < 32; i += 8)
        t[ty + i][tx] = src[(size_t)(r0 + ty + i) * 512 + c0 + tx];
    __syncthreads();
    if (tid < 128) {
        const int n  = c0 + (tid >> 2);        // packed row (0..511)
        const int k0 = r0 + (tid & 3) * 8;     // packed col base (8-aligned)
        half8 o;
        #pragma unroll
        for (int j2 = 0; j2 < 8; ++j2)
            o[j2] = (_Float16)t[(tid & 3) * 8 + j2][tid >> 2];
        *(half8*)&dst[(size_t)(((n >> 6) * KT + (k0 >> 6)) * 8 + ((k0 >> 3) & 7)) * 512
                      + (n & 63) * 8] = o;
    }
}

// ---- fused: in-GEMM h0 || bucket fill || deferred msg/upd transposes -------
__global__ __launch_bounds__(256) void fill_ingemm(
    const int* __restrict__ eidx, int* __restrict__ cursor,
    int* __restrict__ srcs, int E,
    const _Float16* __restrict__ xb, const _Float16* __restrict__ WinT,
    const float* __restrict__ b_in, _Float16* __restrict__ B0,
    int M, int Mtiles,
    const float* __restrict__ msg_W, _Float16* __restrict__ msgT,
    const float* __restrict__ upd_W, _Float16* __restrict__ updT)
{
    const int gemmU = ((Mtiles + 7) >> 3) * 64;
    const int fillU = (E + 255) >> 8;
    const int b = blockIdx.x;
    if (b < gemmU) {
        gemm_body<false, 0, 4, 4, 0>(b, xb, WinT, b_in, B0,
            M, Mtiles, nullptr, nullptr, nullptr, nullptr);
        return;
    }
    if (b < gemmU + fillU) {
        const int e = (b - gemmU) * 256 + threadIdx.x;
        if (e < E) {
            const int d = eidx[E + e];
            const int pos = atomicAdd(&cursor[d], 1);
            if (pos < 64) srcs[d * 64 + pos] = eidx[e];   // never clamps: P~e^-30
        }
        return;
    }
    const int tB = b - gemmU - fillU;          // 0..1535
    if (tB < 256)       transpose_unit(msg_W,              msgT,              512,  tB);
    else if (tB < 512)  transpose_unit(msg_W + 512 * 512,  msgT + 512 * 512,  512,  tB - 256);
    else if (tB < 1024) transpose_unit(upd_W,              updT,              1024, tB - 512);
    else                transpose_unit(upd_W + 1024 * 512, updT + 512 * 1024, 1024, tB - 1024);
}

// --- prep: WinT transpose + x cast->packed + zero cursor & d_out -----------
__global__ __launch_bounds__(256) void prep(
    const float* __restrict__ W_in,  _Float16* __restrict__ WinT,
    const float* __restrict__ x,     _Float16* __restrict__ xb,
    int* __restrict__ cursor, float* __restrict__ outz,
    int n4, int M)
{
    const int b = blockIdx.x;
    const int tid = threadIdx.x;
    const int castU = (n4 + 255) >> 8;
    if (b < 128) {
        transpose_unit(W_in, WinT, 256, b);
    } else if (b < 128 + castU) {
        const int i = (b - 128) * 256 + tid;
        if (i < n4) {
            const float4 v = *(const float4*)(x + (size_t)i * 4);
            ushort4 s;
            union { _Float16 h; unsigned short u; } cv;
            cv.h = (_Float16)v.x; s.x = cv.u;
            cv.h = (_Float16)v.y; s.y = cv.u;
            cv.h = (_Float16)v.z; s.z = cv.u;
            cv.h = (_Float16)v.w; s.w = cv.u;
            const int f = i * 4;                 // flat half idx in [M,256]
            const int m = f >> 8, k = f & 255;
            *(ushort4*)((unsigned short*)xb
                + (size_t)(((m >> 6) * 4 + (k >> 6)) * 8 + ((k >> 3) & 7)) * 512
                + (m & 63) * 8 + (k & 7)) = s;
        }
    } else {
        const int zi = (b - 128 - castU) * 256 + tid;
        if (zi < M) { cursor[zi] = 0; outz[zi] = 0.f; }
    }
}

extern "C" void kernel_launch(void* const* d_in, const int* in_sizes, int n_in,
                              void* d_out, int out_size, void* d_ws, size_t ws_size,
                              hipStream_t stream)
{
    const float* x     = (const float*)d_in[0];
    const int*   eidx  = (const int*)  d_in[1];
    const float* W_in  = (const float*)d_in[2];
    const float* b_in  = (const float*)d_in[3];
    const float* msg_W = (const float*)d_in[4];
    const float* msg_b = (const float*)d_in[5];
    const float* upd_W = (const float*)d_in[6];
    const float* upd_b = (const float*)d_in[7];
    const float* W_out = (const float*)d_in[8];
    const float* b_out = (const float*)d_in[9];

    const int IN = 256, H = 512;
    const int M = in_sizes[0] / IN;   // 10000
    const int E = in_sizes[1] / 2;    // 160000
    const int Mtiles = (M + 63) / 64;
    const size_t Mt64 = (size_t)Mtiles * 64;

    _Float16* xb   = (_Float16*)d_ws;           // packed [Mt64, 256]
    _Float16* B0   = xb + Mt64 * IN;            // packed or row-major [Mt64,512]
    _Float16* B1   = B0 + Mt64 * H;
    _Float16* B2   = B1 + Mt64 * H;             // packed aggr
    _Float16* WinT = B2 + Mt64 * H;             // packed [512,256]
    _Float16* msgT = WinT + (size_t)H * IN;     // packed [2][512,512]
    _Float16* updT = msgT + (size_t)2 * H * H;  // packed [2][512,1024]
    int* cursor = (int*)(updT + (size_t)2 * H * 2 * H);   // [M]
    int* srcs   = cursor + M;                   // [M*64] dst-buckets
    _Float16* Pbuf = (_Float16*)(srcs + (size_t)M * 64);  // frag-layout [Mt64,512]

    const dim3 blk(256);
    const int gemmBlocks = ((Mtiles + 7) / 8) * 64;      // 1280
    const int aggrU = ((M + 15) / 16) * 4;               // 2500 (quarter units)

    const int n4 = M * IN / 4;
    const int castU = (n4 + 255) / 256;
    const int fillU = (E + 255) / 256;
    const int zeroU = (M + 255) / 256;
    const int transU = 1536;                    // 256+256 msg + 512+512 upd tiles

    // prep: WinT + x cast + zero(cursor, d_out)
    prep<<<dim3(128 + castU + zeroU), blk, 0, stream>>>(
        W_in, WinT, x, xb, cursor, (float*)d_out, n4, M);
    // in-GEMM h0 || bucket fill || deferred msg/upd transposes
    fill_ingemm<<<dim3(gemmBlocks + fillU + transU), blk, 0, stream>>>(
        eidx, cursor, srcs, E, xb, WinT, b_in, B0, M, Mtiles,
        msg_W, msgT, upd_W, updT);

    // layer 0
    gemm_msg<<<dim3(gemmBlocks), blk, 0, stream>>>(
        B0, msgT, msg_b, B1, M, Mtiles);                 // msg0 -> B1 row-major
    aggp<<<dim3(gemmBlocks + aggrU), blk, 0, stream>>>(
        B1, cursor, srcs, B2, M,
        B0, updT, Pbuf, Mtiles, gemmBlocks);             // P0 || aggr0
    gemm_upd_pack<<<dim3(gemmBlocks), blk, 0, stream>>>(
        B2, updT, upd_b, B1, M, Mtiles, Pbuf);           // upd0 -> B1 packed
    // layer 1
    gemm_msg<<<dim3(gemmBlocks), blk, 0, stream>>>(
        B1, msgT + 512 * 512, msg_b + 512, B0, M, Mtiles); // msg1 -> B0 row-major
    aggp<<<dim3(gemmBlocks + aggrU), blk, 0, stream>>>(
        B0, cursor, srcs, B2, M,
        B1, updT + 512 * 1024, Pbuf, Mtiles, gemmBlocks);  // P1 || aggr1
    gemm_upd_out<<<dim3(gemmBlocks), blk, 0, stream>>>(
        B2, updT + 512 * 1024, upd_b + 512, M, Mtiles, Pbuf,
        W_out, b_out, (float*)d_out);
}